// Round 1
// baseline (667.741 us; speedup 1.0000x reference)
//
#include <hip/hip_runtime.h>
#include <hip/hip_bf16.h>
#include <stdint.h>

#define B_ 4
#define S_ 2048
#define E_ 2048
#define H_ 16
#define D_ 128
#define M_ (B_ * S_)  // 8192 rows

typedef unsigned short ushort_t;
typedef unsigned int uint_t;
typedef __attribute__((ext_vector_type(4))) float f32x4;
typedef __attribute__((ext_vector_type(8))) short bf16x8;

__device__ __forceinline__ ushort_t f2bf(float f) {
  uint_t u = __float_as_uint(f);
  u += 0x7FFFu + ((u >> 16) & 1u);  // RNE
  return (ushort_t)(u >> 16);
}
__device__ __forceinline__ float bf2f(ushort_t h) {
  return __uint_as_float(((uint_t)h) << 16);
}

#define GLOAD_LDS16(gp, lp)                                   \
  __builtin_amdgcn_global_load_lds(                           \
      (__attribute__((address_space(1))) void*)(gp),          \
      (__attribute__((address_space(3))) void*)(lp), 16, 0, 0)

__device__ __forceinline__ float qmax16(float v) {
  v = fmaxf(v, __shfl_xor(v, 1));
  v = fmaxf(v, __shfl_xor(v, 2));
  v = fmaxf(v, __shfl_xor(v, 4));
  v = fmaxf(v, __shfl_xor(v, 8));
  return v;
}
__device__ __forceinline__ float qsum16(float v) {
  v += __shfl_xor(v, 1);
  v += __shfl_xor(v, 2);
  v += __shfl_xor(v, 4);
  v += __shfl_xor(v, 8);
  return v;
}

// ---------------------------------------------------------------- converts
__global__ void f32_to_bf16(const float* __restrict__ in, ushort_t* __restrict__ out,
                            size_t n4) {
  const size_t stride = (size_t)gridDim.x * blockDim.x;
  for (size_t i = (size_t)blockIdx.x * blockDim.x + threadIdx.x; i < n4; i += stride) {
    float4 f = ((const float4*)in)[i];
    uint_t lo = (uint_t)f2bf(f.x) | ((uint_t)f2bf(f.y) << 16);
    uint_t hi = (uint_t)f2bf(f.z) | ((uint_t)f2bf(f.w) << 16);
    ((uint2*)out)[i] = make_uint2(lo, hi);
  }
}

// ---------------------------------------------------------------- RoPE (in place, bf16 [M][E])
__global__ void rope_k(ushort_t* __restrict__ T) {
  const size_t total = (size_t)M_ * (E_ / 8);
  const size_t stride = (size_t)gridDim.x * blockDim.x;
  for (size_t c = (size_t)blockIdx.x * blockDim.x + threadIdx.x; c < total; c += stride) {
    const int row = (int)(c >> 8);       // E_/8 = 256 chunks per row
    const int ch = (int)(c & 255);
    const int s = row & (S_ - 1);
    const int p0 = ((ch * 8) & (D_ - 1)) >> 1;  // first pair index within head
    ushort_t* p = T + ((size_t)row << 11) + ch * 8;
    bf16x8 v = *(bf16x8*)p;
#pragma unroll
    for (int j = 0; j < 4; j++) {
      const int ip = p0 + j;
      const float inv = __expf(-0.14391156963595867f * (float)ip);  // 10000^(-2ip/128)
      const float ang = (float)s * inv;
      float sn, cs;
      sincosf(ang, &sn, &cs);
      const float xe = bf2f((ushort_t)v[2 * j]);
      const float xo = bf2f((ushort_t)v[2 * j + 1]);
      v[2 * j] = (short)f2bf(xe * cs - xo * sn);
      v[2 * j + 1] = (short)f2bf(xe * sn + xo * cs);
    }
    *(bf16x8*)p = v;
  }
}

// ---------------------------------------------------------------- V transpose: [M][E] -> [B][H][D][S]
__global__ __launch_bounds__(256) void transpose_v(const ushort_t* __restrict__ Vp,
                                                   ushort_t* __restrict__ Vt) {
  const int b = blockIdx.z, h = blockIdx.y;
  const int s0 = blockIdx.x * 64;
  const int tid = threadIdx.x;
  __shared__ ushort_t T[64][136];
#pragma unroll
  for (int i = 0; i < 4; i++) {
    const int c = i * 256 + tid;
    const int s = c >> 4, d8 = c & 15;
    *(bf16x8*)(&T[s][d8 * 8]) =
        *(const bf16x8*)(Vp + (size_t)(b * S_ + s0 + s) * E_ + h * D_ + d8 * 8);
  }
  __syncthreads();
#pragma unroll
  for (int i = 0; i < 4; i++) {
    const int c = i * 256 + tid;
    const int d = c >> 3, s8 = c & 7;
    bf16x8 v;
#pragma unroll
    for (int j = 0; j < 8; j++) v[j] = (short)T[s8 * 8 + j][d];
    *(bf16x8*)(Vt + ((size_t)(b * H_ + h) * D_ + d) * S_ + s0 + s8 * 8) = v;
  }
}

// ---------------------------------------------------------------- GEMM: C[M][N] = A[M][K]·Bw[N][K]^T + bias
// m97-style: 128x128 tile, BK=64, global_load_lds(16B) with pre-swizzled source,
// swizzled ds_read_b128 (rule #21: linear dest + inverse-swz source + swz read).
template <int OUTF32>
__global__ __launch_bounds__(256, 2) void gemm_bt(const ushort_t* __restrict__ A,
                                                  const ushort_t* __restrict__ Bw,
                                                  const float* __restrict__ bias,
                                                  void* __restrict__ Cv) {
  __shared__ ushort_t As[128 * 64];
  __shared__ ushort_t Bs[128 * 64];
  const int tid = threadIdx.x;
  const int w = tid >> 6, l = tid & 63, g = l >> 4, ln = l & 15;
  const int wm = w >> 1, wn = w & 1;
  // XCD-bijective swizzle (1024 % 8 == 0)
  const int flat = blockIdx.y * 16 + blockIdx.x;
  const int swz = (flat & 7) * 128 + (flat >> 3);
  const int m0 = (swz >> 4) * 128, n0 = (swz & 15) * 128;

  f32x4 acc[4][4];
#pragma unroll
  for (int i = 0; i < 4; i++)
#pragma unroll
    for (int j = 0; j < 4; j++)
#pragma unroll
      for (int r = 0; r < 4; r++) acc[i][j][r] = 0.f;

  const ushort_t* Ab = A + (size_t)m0 * E_;
  const ushort_t* Bb = Bw + (size_t)n0 * E_;

  for (int k0 = 0; k0 < E_; k0 += 64) {
    __syncthreads();
#pragma unroll
    for (int i = 0; i < 4; i++) {
      const int c = i * 256 + tid;
      const int row = c >> 3;                  // 8 x 16B chunks per 64-elem row
      const int gs = (c & 7) ^ (row & 7);      // inverse-swizzled global source
      GLOAD_LDS16(Ab + (size_t)row * E_ + k0 + gs * 8, (char*)As + (i * 256 + w * 64) * 16);
      GLOAD_LDS16(Bb + (size_t)row * E_ + k0 + gs * 8, (char*)Bs + (i * 256 + w * 64) * 16);
    }
    __syncthreads();
#pragma unroll
    for (int kk = 0; kk < 2; kk++) {
      bf16x8 af[4], bfr[4];
#pragma unroll
      for (int mi = 0; mi < 4; mi++) {
        const int row = wm * 64 + mi * 16 + ln;
        const int sl = (kk * 4 + g) ^ (row & 7);
        af[mi] = *(const bf16x8*)(As + row * 64 + sl * 8);
      }
#pragma unroll
      for (int ni = 0; ni < 4; ni++) {
        const int row = wn * 64 + ni * 16 + ln;
        const int sl = (kk * 4 + g) ^ (row & 7);
        bfr[ni] = *(const bf16x8*)(Bs + row * 64 + sl * 8);
      }
#pragma unroll
      for (int mi = 0; mi < 4; mi++)
#pragma unroll
        for (int ni = 0; ni < 4; ni++)
          acc[mi][ni] =
              __builtin_amdgcn_mfma_f32_16x16x32_bf16(af[mi], bfr[ni], acc[mi][ni], 0, 0, 0);
    }
  }

  float bv[4];
#pragma unroll
  for (int ni = 0; ni < 4; ni++) bv[ni] = bias[n0 + wn * 64 + ni * 16 + ln];
#pragma unroll
  for (int mi = 0; mi < 4; mi++)
#pragma unroll
    for (int ni = 0; ni < 4; ni++)
#pragma unroll
      for (int r = 0; r < 4; r++) {
        const float v = acc[mi][ni][r] + bv[ni];
        const size_t row = m0 + wm * 64 + mi * 16 + g * 4 + r;
        const size_t col = n0 + wn * 64 + ni * 16 + ln;
        if (OUTF32)
          ((float*)Cv)[row * E_ + col] = v;
        else
          ((ushort_t*)Cv)[row * E_ + col] = f2bf(v);
      }
}

// ---------------------------------------------------------------- flash attention (causal)
// 128 q-rows/block, 4 waves x 32 rows, KV tile 64. Q in regs; K,Vt XOR-swizzled LDS;
// P through padded per-wave LDS (stride 72 -> 2-way max).
__global__ __launch_bounds__(256, 2) void attn_fwd(const ushort_t* __restrict__ Q,
                                                   const ushort_t* __restrict__ K,
                                                   const ushort_t* __restrict__ Vt,
                                                   ushort_t* __restrict__ O) {
  const int b = blockIdx.z, h = blockIdx.y;
  const int q0 = blockIdx.x * 128;
  const int tid = threadIdx.x;
  const int w = tid >> 6, l = tid & 63, g = l >> 4, ln = l & 15;
  const int wrow0 = q0 + w * 32;

  __shared__ ushort_t Ks[64 * 128];
  __shared__ ushort_t Vs[128 * 64];
  __shared__ ushort_t Ps[4][32 * 72];

  bf16x8 qf[2][4];
  {
    const ushort_t* qb = Q + (size_t)(b * S_ + wrow0) * E_ + h * D_;
#pragma unroll
    for (int mi = 0; mi < 2; mi++)
#pragma unroll
      for (int kk = 0; kk < 4; kk++)
        qf[mi][kk] = *(const bf16x8*)(qb + (size_t)(mi * 16 + ln) * E_ + kk * 32 + g * 8);
  }

  f32x4 oacc[2][8];
#pragma unroll
  for (int mi = 0; mi < 2; mi++)
#pragma unroll
    for (int nd = 0; nd < 8; nd++)
#pragma unroll
      for (int r = 0; r < 4; r++) oacc[mi][nd][r] = 0.f;
  float mrun[2][4], srun[2][4];
#pragma unroll
  for (int mi = 0; mi < 2; mi++)
#pragma unroll
    for (int r = 0; r < 4; r++) {
      mrun[mi][r] = -__builtin_inff();
      srun[mi][r] = 0.f;
    }

  const ushort_t* Kb = K + (size_t)(b * S_) * E_ + h * D_;
  const ushort_t* Vb = Vt + (size_t)(b * H_ + h) * D_ * S_;
  const float scale = 0.08838834764831845f;  // D^-0.5
  const int nt = (q0 + 128) / 64;

  for (int t = 0; t < nt; t++) {
    const int kv0 = t * 64;
    __syncthreads();  // prev PV reads of Ks/Vs done
#pragma unroll
    for (int i = 0; i < 4; i++) {  // stage K tile [64][128], swizzled
      const int c = i * 256 + tid;
      const int row = c >> 4, sl = c & 15;
      const int dsl = sl ^ (row & 7);
      *(bf16x8*)(Ks + row * 128 + dsl * 8) =
          *(const bf16x8*)(Kb + (size_t)(kv0 + row) * E_ + sl * 8);
    }
#pragma unroll
    for (int i = 0; i < 4; i++) {  // stage Vt tile [128][64], swizzled
      const int c = i * 256 + tid;
      const int row = c >> 3, sl = c & 7;
      const int dsl = sl ^ (row & 7);
      *(bf16x8*)(Vs + row * 64 + dsl * 8) =
          *(const bf16x8*)(Vb + (size_t)row * S_ + kv0 + sl * 8);
    }
    __syncthreads();
    const bool active = kv0 <= wrow0 + 31;  // wave-level causal skip
    if (active) {
      f32x4 sa[2][4];
#pragma unroll
      for (int mi = 0; mi < 2; mi++)
#pragma unroll
        for (int ni = 0; ni < 4; ni++)
#pragma unroll
          for (int r = 0; r < 4; r++) sa[mi][ni][r] = 0.f;
#pragma unroll
      for (int kk = 0; kk < 4; kk++) {
        bf16x8 kf[4];
#pragma unroll
        for (int ni = 0; ni < 4; ni++) {
          const int row = ni * 16 + ln;
          const int sl = (kk * 4 + g) ^ (row & 7);
          kf[ni] = *(const bf16x8*)(Ks + row * 128 + sl * 8);
        }
#pragma unroll
        for (int mi = 0; mi < 2; mi++)
#pragma unroll
          for (int ni = 0; ni < 4; ni++)
            sa[mi][ni] =
                __builtin_amdgcn_mfma_f32_16x16x32_bf16(qf[mi][kk], kf[ni], sa[mi][ni], 0, 0, 0);
      }
      // online softmax (rows: mi*16 + g*4 + r; cols across ln and ni)
#pragma unroll
      for (int mi = 0; mi < 2; mi++)
#pragma unroll
        for (int r = 0; r < 4; r++) {
          const int rowq = wrow0 + mi * 16 + g * 4 + r;
          float vmax = -__builtin_inff();
#pragma unroll
          for (int ni = 0; ni < 4; ni++) {
            float v = sa[mi][ni][r] * scale;
            const int col = kv0 + ni * 16 + ln;
            if (col > rowq) v = -__builtin_inff();
            sa[mi][ni][r] = v;
            vmax = fmaxf(vmax, v);
          }
          vmax = qmax16(vmax);
          const float mnew = fmaxf(mrun[mi][r], vmax);
          const float fs = __expf(mrun[mi][r] - mnew);
          mrun[mi][r] = mnew;
          float psum = 0.f;
#pragma unroll
          for (int ni = 0; ni < 4; ni++) {
            const float p = __expf(sa[mi][ni][r] - mnew);
            sa[mi][ni][r] = p;
            psum += p;
          }
          psum = qsum16(psum);
          srun[mi][r] = srun[mi][r] * fs + psum;
#pragma unroll
          for (int nd = 0; nd < 8; nd++) oacc[mi][nd][r] *= fs;
        }
      // P -> LDS (bf16), padded stride 72
#pragma unroll
      for (int mi = 0; mi < 2; mi++)
#pragma unroll
        for (int ni = 0; ni < 4; ni++)
#pragma unroll
          for (int r = 0; r < 4; r++)
            Ps[w][(mi * 16 + g * 4 + r) * 72 + ni * 16 + ln] = f2bf(sa[mi][ni][r]);
    }
    __syncthreads();  // (also orders P write -> P read)
    if (active) {
#pragma unroll
      for (int ks = 0; ks < 2; ks++) {
        bf16x8 pf[2];
#pragma unroll
        for (int mi = 0; mi < 2; mi++)
          pf[mi] = *(const bf16x8*)(&Ps[w][(mi * 16 + ln) * 72 + ks * 32 + g * 8]);
#pragma unroll
        for (int nd = 0; nd < 8; nd++) {
          const int row = nd * 16 + ln;
          const int sl = (ks * 4 + g) ^ (row & 7);
          const bf16x8 vf = *(const bf16x8*)(Vs + row * 64 + sl * 8);
#pragma unroll
          for (int mi = 0; mi < 2; mi++)
            oacc[mi][nd] = __builtin_amdgcn_mfma_f32_16x16x32_bf16(pf[mi], vf, oacc[mi][nd], 0, 0, 0);
        }
      }
    }
  }

  ushort_t* Ob = O + (size_t)(b * S_ + wrow0) * E_ + h * D_;
#pragma unroll
  for (int mi = 0; mi < 2; mi++) {
    float inv[4];
#pragma unroll
    for (int r = 0; r < 4; r++) inv[r] = 1.0f / srun[mi][r];
#pragma unroll
    for (int nd = 0; nd < 8; nd++)
#pragma unroll
      for (int r = 0; r < 4; r++)
        Ob[(size_t)(mi * 16 + g * 4 + r) * E_ + nd * 16 + ln] = f2bf(oacc[mi][nd][r] * inv[r]);
  }
}

// ---------------------------------------------------------------- launch
extern "C" void kernel_launch(void* const* d_in, const int* in_sizes, int n_in,
                              void* d_out, int out_size, void* d_ws, size_t ws_size,
                              hipStream_t stream) {
  const float* x = (const float*)d_in[0];
  const float* Wq = (const float*)d_in[1];
  const float* bq = (const float*)d_in[2];
  const float* Wk = (const float*)d_in[3];
  const float* bk = (const float*)d_in[4];
  const float* Wv = (const float*)d_in[5];
  const float* bv = (const float*)d_in[6];
  const float* Wo = (const float*)d_in[7];
  const float* bo = (const float*)d_in[8];
  float* out = (float*)d_out;

  // workspace layout (bf16 elements): needs 6*SZ*2 = 201,326,592 bytes
  ushort_t* ws = (ushort_t*)d_ws;
  const size_t SZ = (size_t)M_ * E_;   // 16,777,216
  const size_t WSZ = (size_t)E_ * E_;  // 4,194,304
  ushort_t* xb = ws;            // x bf16; reused as attention output after projections
  ushort_t* Qb = ws + SZ;
  ushort_t* Kb = ws + 2 * SZ;
  ushort_t* Vb = ws + 3 * SZ;
  ushort_t* Vtb = ws + 4 * SZ;
  ushort_t* Wqb = ws + 5 * SZ;
  ushort_t* Wkb = Wqb + WSZ;
  ushort_t* Wvb = Wkb + WSZ;
  ushort_t* Wob = Wvb + WSZ;
  ushort_t* Ob = xb;

  f32_to_bf16<<<2048, 256, 0, stream>>>(x, xb, SZ / 4);
  f32_to_bf16<<<1024, 256, 0, stream>>>(Wq, Wqb, WSZ / 4);
  f32_to_bf16<<<1024, 256, 0, stream>>>(Wk, Wkb, WSZ / 4);
  f32_to_bf16<<<1024, 256, 0, stream>>>(Wv, Wvb, WSZ / 4);
  f32_to_bf16<<<1024, 256, 0, stream>>>(Wo, Wob, WSZ / 4);

  dim3 gg(16, 64);
  gemm_bt<0><<<gg, 256, 0, stream>>>(xb, Wqb, bq, Qb);
  gemm_bt<0><<<gg, 256, 0, stream>>>(xb, Wkb, bk, Kb);
  gemm_bt<0><<<gg, 256, 0, stream>>>(xb, Wvb, bv, Vb);

  rope_k<<<2048, 256, 0, stream>>>(Qb);
  rope_k<<<2048, 256, 0, stream>>>(Kb);
  transpose_v<<<dim3(32, H_, B_), 256, 0, stream>>>(Vb, Vtb);

  attn_fwd<<<dim3(16, H_, B_), 256, 0, stream>>>(Qb, Kb, Vtb, Ob);

  gemm_bt<1><<<gg, 256, 0, stream>>>(Ob, Wob, bo, (void*)out);
}

// Round 2
// 618.010 us; speedup vs baseline: 1.0805x; 1.0805x over previous
//
#include <hip/hip_runtime.h>
#include <hip/hip_bf16.h>
#include <stdint.h>

#define B_ 4
#define S_ 2048
#define E_ 2048
#define H_ 16
#define D_ 128
#define M_ (B_ * S_)  // 8192 rows

typedef unsigned short ushort_t;
typedef unsigned int uint_t;
typedef __attribute__((ext_vector_type(4))) float f32x4;
typedef __attribute__((ext_vector_type(8))) short bf16x8;

__device__ __forceinline__ ushort_t f2bf(float f) {
  uint_t u = __float_as_uint(f);
  u += 0x7FFFu + ((u >> 16) & 1u);  // RNE
  return (ushort_t)(u >> 16);
}
__device__ __forceinline__ float bf2f(ushort_t h) {
  return __uint_as_float(((uint_t)h) << 16);
}

#define GLOAD_LDS16(gp, lp)                                   \
  __builtin_amdgcn_global_load_lds(                           \
      (__attribute__((address_space(1))) void*)(gp),          \
      (__attribute__((address_space(3))) void*)(lp), 16, 0, 0)

__device__ __forceinline__ float qmax16(float v) {
  v = fmaxf(v, __shfl_xor(v, 1));
  v = fmaxf(v, __shfl_xor(v, 2));
  v = fmaxf(v, __shfl_xor(v, 4));
  v = fmaxf(v, __shfl_xor(v, 8));
  return v;
}
__device__ __forceinline__ float qsum16(float v) {
  v += __shfl_xor(v, 1);
  v += __shfl_xor(v, 2);
  v += __shfl_xor(v, 4);
  v += __shfl_xor(v, 8);
  return v;
}

// ---------------------------------------------------------------- converts
__global__ void f32_to_bf16(const float* __restrict__ in, ushort_t* __restrict__ out,
                            size_t n4) {
  const size_t stride = (size_t)gridDim.x * blockDim.x;
  for (size_t i = (size_t)blockIdx.x * blockDim.x + threadIdx.x; i < n4; i += stride) {
    float4 f = ((const float4*)in)[i];
    uint_t lo = (uint_t)f2bf(f.x) | ((uint_t)f2bf(f.y) << 16);
    uint_t hi = (uint_t)f2bf(f.z) | ((uint_t)f2bf(f.w) << 16);
    ((uint2*)out)[i] = make_uint2(lo, hi);
  }
}

// ---------------------------------------------------------------- RoPE (in place, bf16 [M][E])
__global__ void rope_k(ushort_t* __restrict__ T) {
  const size_t total = (size_t)M_ * (E_ / 8);
  const size_t stride = (size_t)gridDim.x * blockDim.x;
  for (size_t c = (size_t)blockIdx.x * blockDim.x + threadIdx.x; c < total; c += stride) {
    const int row = (int)(c >> 8);       // E_/8 = 256 chunks per row
    const int ch = (int)(c & 255);
    const int s = row & (S_ - 1);
    const int p0 = ((ch * 8) & (D_ - 1)) >> 1;  // first pair index within head
    ushort_t* p = T + ((size_t)row << 11) + ch * 8;
    bf16x8 v = *(bf16x8*)p;
#pragma unroll
    for (int j = 0; j < 4; j++) {
      const int ip = p0 + j;
      const float inv = __expf(-0.14391156963595867f * (float)ip);  // 10000^(-2ip/128)
      const float ang = (float)s * inv;
      float sn, cs;
      sincosf(ang, &sn, &cs);
      const float xe = bf2f((ushort_t)v[2 * j]);
      const float xo = bf2f((ushort_t)v[2 * j + 1]);
      v[2 * j] = (short)f2bf(xe * cs - xo * sn);
      v[2 * j + 1] = (short)f2bf(xe * sn + xo * cs);
    }
    *(bf16x8*)p = v;
  }
}

// ---------------------------------------------------------------- V transpose: [M][E] -> [B][H][D][S]
__global__ __launch_bounds__(256) void transpose_v(const ushort_t* __restrict__ Vp,
                                                   ushort_t* __restrict__ Vt) {
  const int b = blockIdx.z, h = blockIdx.y;
  const int s0 = blockIdx.x * 64;
  const int tid = threadIdx.x;
  __shared__ ushort_t T[64][136];
#pragma unroll
  for (int i = 0; i < 4; i++) {
    const int c = i * 256 + tid;
    const int s = c >> 4, d8 = c & 15;
    *(bf16x8*)(&T[s][d8 * 8]) =
        *(const bf16x8*)(Vp + (size_t)(b * S_ + s0 + s) * E_ + h * D_ + d8 * 8);
  }
  __syncthreads();
#pragma unroll
  for (int i = 0; i < 4; i++) {
    const int c = i * 256 + tid;
    const int d = c >> 3, s8 = c & 7;
    bf16x8 v;
#pragma unroll
    for (int j = 0; j < 8; j++) v[j] = (short)T[s8 * 8 + j][d];
    *(bf16x8*)(Vt + ((size_t)(b * H_ + h) * D_ + d) * S_ + s0 + s8 * 8) = v;
  }
}

// ---------------------------------------------------------------- GEMM: C[M][N] = A[M][K]·Bw[N][K]^T + bias
template <int OUTF32>
__global__ __launch_bounds__(256, 2) void gemm_bt(const ushort_t* __restrict__ A,
                                                  const ushort_t* __restrict__ Bw,
                                                  const float* __restrict__ bias,
                                                  void* __restrict__ Cv) {
  __shared__ ushort_t As[128 * 64];
  __shared__ ushort_t Bs[128 * 64];
  const int tid = threadIdx.x;
  const int w = tid >> 6, l = tid & 63, g = l >> 4, ln = l & 15;
  const int wm = w >> 1, wn = w & 1;
  const int flat = blockIdx.y * 16 + blockIdx.x;
  const int swz = (flat & 7) * 128 + (flat >> 3);
  const int m0 = (swz >> 4) * 128, n0 = (swz & 15) * 128;

  f32x4 acc[4][4];
#pragma unroll
  for (int i = 0; i < 4; i++)
#pragma unroll
    for (int j = 0; j < 4; j++)
#pragma unroll
      for (int r = 0; r < 4; r++) acc[i][j][r] = 0.f;

  const ushort_t* Ab = A + (size_t)m0 * E_;
  const ushort_t* Bb = Bw + (size_t)n0 * E_;

  for (int k0 = 0; k0 < E_; k0 += 64) {
    __syncthreads();
#pragma unroll
    for (int i = 0; i < 4; i++) {
      const int c = i * 256 + tid;
      const int row = c >> 3;
      const int gs = (c & 7) ^ (row & 7);
      GLOAD_LDS16(Ab + (size_t)row * E_ + k0 + gs * 8, (char*)As + (i * 256 + w * 64) * 16);
      GLOAD_LDS16(Bb + (size_t)row * E_ + k0 + gs * 8, (char*)Bs + (i * 256 + w * 64) * 16);
    }
    __syncthreads();
#pragma unroll
    for (int kk = 0; kk < 2; kk++) {
      bf16x8 af[4], bfr[4];
#pragma unroll
      for (int mi = 0; mi < 4; mi++) {
        const int row = wm * 64 + mi * 16 + ln;
        const int sl = (kk * 4 + g) ^ (row & 7);
        af[mi] = *(const bf16x8*)(As + row * 64 + sl * 8);
      }
#pragma unroll
      for (int ni = 0; ni < 4; ni++) {
        const int row = wn * 64 + ni * 16 + ln;
        const int sl = (kk * 4 + g) ^ (row & 7);
        bfr[ni] = *(const bf16x8*)(Bs + row * 64 + sl * 8);
      }
#pragma unroll
      for (int mi = 0; mi < 4; mi++)
#pragma unroll
        for (int ni = 0; ni < 4; ni++)
          acc[mi][ni] =
              __builtin_amdgcn_mfma_f32_16x16x32_bf16(af[mi], bfr[ni], acc[mi][ni], 0, 0, 0);
    }
  }

  float bv[4];
#pragma unroll
  for (int ni = 0; ni < 4; ni++) bv[ni] = bias[n0 + wn * 64 + ni * 16 + ln];
#pragma unroll
  for (int mi = 0; mi < 4; mi++)
#pragma unroll
    for (int ni = 0; ni < 4; ni++)
#pragma unroll
      for (int r = 0; r < 4; r++) {
        const float v = acc[mi][ni][r] + bv[ni];
        const size_t row = m0 + wm * 64 + mi * 16 + g * 4 + r;
        const size_t col = n0 + wn * 64 + ni * 16 + ln;
        if (OUTF32)
          ((float*)Cv)[row * E_ + col] = v;
        else
          ((ushort_t*)Cv)[row * E_ + col] = f2bf(v);
      }
}

// ---------------------------------------------------------------- flash attention (causal), v2
// 256 q-rows/block, 8 waves x 32 rows, KV tile 64. Double-buffered K/V via
// global_load_lds (issue-early, single barrier per tile). Q pre-scaled in regs.
// P per-wave through padded LDS (no cross-wave barrier needed: lgkmcnt only).
__global__ __launch_bounds__(512, 2) void attn_fwd(const ushort_t* __restrict__ Q,
                                                   const ushort_t* __restrict__ K,
                                                   const ushort_t* __restrict__ Vt,
                                                   ushort_t* __restrict__ O) {
  const int b = blockIdx.z, h = blockIdx.y;
  const int q0 = blockIdx.x * 256;
  const int tid = threadIdx.x;
  const int w = tid >> 6, l = tid & 63, g = l >> 4, ln = l & 15;
  const int wrow0 = q0 + w * 32;

  __shared__ ushort_t Ks[2][64 * 128];
  __shared__ ushort_t Vs[2][128 * 64];
  __shared__ ushort_t Ps[8][32 * 72];

  const float scale = 0.08838834764831845f;  // D^-0.5
  bf16x8 qf[2][4];
  {
    const ushort_t* qb = Q + (size_t)(b * S_ + wrow0) * E_ + h * D_;
#pragma unroll
    for (int mi = 0; mi < 2; mi++)
#pragma unroll
      for (int kk = 0; kk < 4; kk++) {
        bf16x8 v = *(const bf16x8*)(qb + (size_t)(mi * 16 + ln) * E_ + kk * 32 + g * 8);
#pragma unroll
        for (int j = 0; j < 8; j++) v[j] = (short)f2bf(bf2f((ushort_t)v[j]) * scale);
        qf[mi][kk] = v;
      }
  }

  f32x4 oacc[2][8];
#pragma unroll
  for (int mi = 0; mi < 2; mi++)
#pragma unroll
    for (int nd = 0; nd < 8; nd++)
#pragma unroll
      for (int r = 0; r < 4; r++) oacc[mi][nd][r] = 0.f;
  float mrun[2][4], srun[2][4];
#pragma unroll
  for (int mi = 0; mi < 2; mi++)
#pragma unroll
    for (int r = 0; r < 4; r++) {
      mrun[mi][r] = -__builtin_inff();
      srun[mi][r] = 0.f;
    }

  const ushort_t* Kb = K + (size_t)(b * S_) * E_ + h * D_;
  const ushort_t* Vb = Vt + (size_t)(b * H_ + h) * D_ * S_;
  const int nt = (q0 + 256) / 64;

  // ---- staging helper (inlined twice): K tile [64][128], V tile [128][64],
  // both-sides swizzle, linear LDS dest (wave-uniform base for gload_lds).
#define STAGE_KV(buf, kv0_)                                                          \
  do {                                                                               \
    _Pragma("unroll") for (int i = 0; i < 2; i++) {                                  \
      const int c = i * 512 + tid;                                                   \
      const int row = c >> 4, sl = c & 15;                                           \
      const int gs = sl ^ (row & 7);                                                 \
      GLOAD_LDS16(Kb + (size_t)((kv0_) + row) * E_ + gs * 8,                         \
                  (char*)(&Ks[buf][0]) + (i * 512 + w * 64) * 16);                   \
    }                                                                                \
    _Pragma("unroll") for (int i = 0; i < 2; i++) {                                  \
      const int c = i * 512 + tid;                                                   \
      const int row = c >> 3, sl = c & 7;                                            \
      const int gs = sl ^ (row & 7);                                                 \
      GLOAD_LDS16(Vb + (size_t)row * S_ + (kv0_) + gs * 8,                           \
                  (char*)(&Vs[buf][0]) + (i * 512 + w * 64) * 16);                   \
    }                                                                                \
  } while (0)

  STAGE_KV(0, 0);
  __syncthreads();  // drains vmcnt(0), tile 0 ready

  for (int t = 0; t < nt; t++) {
    const int kv0 = t * 64;
    const int cur = t & 1;
    if (t + 1 < nt) STAGE_KV(cur ^ 1, kv0 + 64);  // in flight during compute

    const bool active = kv0 <= wrow0 + 31;
    if (active) {
      const ushort_t* Kst = &Ks[cur][0];
      const ushort_t* Vst = &Vs[cur][0];
      // ---- QK^T (Q pre-scaled)
      f32x4 sa[2][4];
#pragma unroll
      for (int mi = 0; mi < 2; mi++)
#pragma unroll
        for (int ni = 0; ni < 4; ni++)
#pragma unroll
          for (int r = 0; r < 4; r++) sa[mi][ni][r] = 0.f;
#pragma unroll
      for (int kk = 0; kk < 4; kk++) {
        bf16x8 kf[4];
#pragma unroll
        for (int ni = 0; ni < 4; ni++) {
          const int row = ni * 16 + ln;
          const int sl = (kk * 4 + g) ^ (row & 7);
          kf[ni] = *(const bf16x8*)(Kst + row * 128 + sl * 8);
        }
#pragma unroll
        for (int mi = 0; mi < 2; mi++)
#pragma unroll
          for (int ni = 0; ni < 4; ni++)
            sa[mi][ni] =
                __builtin_amdgcn_mfma_f32_16x16x32_bf16(qf[mi][kk], kf[ni], sa[mi][ni], 0, 0, 0);
      }
      // ---- causal mask only on diagonal tiles
      if (kv0 + 63 > wrow0) {
#pragma unroll
        for (int mi = 0; mi < 2; mi++)
#pragma unroll
          for (int r = 0; r < 4; r++) {
            const int rowq = wrow0 + mi * 16 + g * 4 + r;
#pragma unroll
            for (int ni = 0; ni < 4; ni++) {
              const int col = kv0 + ni * 16 + ln;
              if (col > rowq) sa[mi][ni][r] = -__builtin_inff();
            }
          }
      }
      // ---- online softmax; rescale only when max grows (exact)
#pragma unroll
      for (int mi = 0; mi < 2; mi++)
#pragma unroll
        for (int r = 0; r < 4; r++) {
          float vmax = fmaxf(fmaxf(sa[mi][0][r], sa[mi][1][r]),
                             fmaxf(sa[mi][2][r], sa[mi][3][r]));
          vmax = qmax16(vmax);
          if (vmax > mrun[mi][r]) {
            const float fs = __expf(mrun[mi][r] - vmax);
            mrun[mi][r] = vmax;
            srun[mi][r] *= fs;
#pragma unroll
            for (int nd = 0; nd < 8; nd++) oacc[mi][nd][r] *= fs;
          }
          const float m = mrun[mi][r];
          float psum = 0.f;
#pragma unroll
          for (int ni = 0; ni < 4; ni++) {
            const float p = __expf(sa[mi][ni][r] - m);
            psum += p;
            Ps[w][(mi * 16 + g * 4 + r) * 72 + ni * 16 + ln] = f2bf(p);
          }
          psum = qsum16(psum);
          srun[mi][r] += psum;
        }
      // per-wave P write -> read ordering (no cross-wave dependency)
      asm volatile("s_waitcnt lgkmcnt(0)" ::: "memory");
      // ---- PV
#pragma unroll
      for (int ks = 0; ks < 2; ks++) {
        bf16x8 pf[2];
#pragma unroll
        for (int mi = 0; mi < 2; mi++)
          pf[mi] = *(const bf16x8*)(&Ps[w][(mi * 16 + ln) * 72 + ks * 32 + g * 8]);
#pragma unroll
        for (int nd = 0; nd < 8; nd++) {
          const int row = nd * 16 + ln;
          const int sl = (ks * 4 + g) ^ (row & 7);
          const bf16x8 vf = *(const bf16x8*)(Vst + row * 64 + sl * 8);
#pragma unroll
          for (int mi = 0; mi < 2; mi++)
            oacc[mi][nd] = __builtin_amdgcn_mfma_f32_16x16x32_bf16(pf[mi], vf, oacc[mi][nd], 0, 0, 0);
        }
      }
    }
    __syncthreads();  // drains vmcnt (next tile staged) + retires this tile's reads
  }
#undef STAGE_KV

  ushort_t* Ob = O + (size_t)(b * S_ + wrow0) * E_ + h * D_;
#pragma unroll
  for (int mi = 0; mi < 2; mi++) {
    float inv[4];
#pragma unroll
    for (int r = 0; r < 4; r++) inv[r] = 1.0f / srun[mi][r];
#pragma unroll
    for (int nd = 0; nd < 8; nd++)
#pragma unroll
      for (int r = 0; r < 4; r++)
        Ob[(size_t)(mi * 16 + g * 4 + r) * E_ + nd * 16 + ln] = f2bf(oacc[mi][nd][r] * inv[r]);
  }
}

// ---------------------------------------------------------------- launch
extern "C" void kernel_launch(void* const* d_in, const int* in_sizes, int n_in,
                              void* d_out, int out_size, void* d_ws, size_t ws_size,
                              hipStream_t stream) {
  const float* x = (const float*)d_in[0];
  const float* Wq = (const float*)d_in[1];
  const float* bq = (const float*)d_in[2];
  const float* Wk = (const float*)d_in[3];
  const float* bk = (const float*)d_in[4];
  const float* Wv = (const float*)d_in[5];
  const float* bv = (const float*)d_in[6];
  const float* Wo = (const float*)d_in[7];
  const float* bo = (const float*)d_in[8];
  float* out = (float*)d_out;

  ushort_t* ws = (ushort_t*)d_ws;
  const size_t SZ = (size_t)M_ * E_;   // 16,777,216
  const size_t WSZ = (size_t)E_ * E_;  // 4,194,304
  ushort_t* xb = ws;            // x bf16; reused as attention output after projections
  ushort_t* Qb = ws + SZ;
  ushort_t* Kb = ws + 2 * SZ;
  ushort_t* Vb = ws + 3 * SZ;
  ushort_t* Vtb = ws + 4 * SZ;
  ushort_t* Wqb = ws + 5 * SZ;
  ushort_t* Wkb = Wqb + WSZ;
  ushort_t* Wvb = Wkb + WSZ;
  ushort_t* Wob = Wvb + WSZ;
  ushort_t* Ob = xb;

  f32_to_bf16<<<2048, 256, 0, stream>>>(x, xb, SZ / 4);
  f32_to_bf16<<<1024, 256, 0, stream>>>(Wq, Wqb, WSZ / 4);
  f32_to_bf16<<<1024, 256, 0, stream>>>(Wk, Wkb, WSZ / 4);
  f32_to_bf16<<<1024, 256, 0, stream>>>(Wv, Wvb, WSZ / 4);
  f32_to_bf16<<<1024, 256, 0, stream>>>(Wo, Wob, WSZ / 4);

  dim3 gg(16, 64);
  gemm_bt<0><<<gg, 256, 0, stream>>>(xb, Wqb, bq, Qb);
  gemm_bt<0><<<gg, 256, 0, stream>>>(xb, Wkb, bk, Kb);
  gemm_bt<0><<<gg, 256, 0, stream>>>(xb, Wvb, bv, Vb);

  rope_k<<<2048, 256, 0, stream>>>(Qb);
  rope_k<<<2048, 256, 0, stream>>>(Kb);
  transpose_v<<<dim3(32, H_, B_), 256, 0, stream>>>(Vb, Vtb);

  attn_fwd<<<dim3(8, H_, B_), 512, 0, stream>>>(Qb, Kb, Vtb, Ob);

  gemm_bt<1><<<gg, 256, 0, stream>>>(Ob, Wob, bo, (void*)out);
}

// Round 3
// 470.539 us; speedup vs baseline: 1.4191x; 1.3134x over previous
//
#include <hip/hip_runtime.h>
#include <hip/hip_bf16.h>
#include <stdint.h>

#define B_ 4
#define S_ 2048
#define E_ 2048
#define H_ 16
#define D_ 128
#define M_ (B_ * S_)  // 8192 rows

typedef unsigned short ushort_t;
typedef unsigned int uint_t;
typedef __attribute__((ext_vector_type(4))) float f32x4;
typedef __attribute__((ext_vector_type(8))) short bf16x8;

__device__ __forceinline__ ushort_t f2bf(float f) {
  uint_t u = __float_as_uint(f);
  u += 0x7FFFu + ((u >> 16) & 1u);  // RNE
  return (ushort_t)(u >> 16);
}
__device__ __forceinline__ float bf2f(ushort_t h) {
  return __uint_as_float(((uint_t)h) << 16);
}
__device__ __forceinline__ uint_t cvt_pk_bf16(float lo, float hi) {
  uint_t r;
  asm("v_cvt_pk_bf16_f32 %0, %1, %2" : "=v"(r) : "v"(lo), "v"(hi));
  return r;
}

#define GLOAD_LDS16(gp, lp)                                   \
  __builtin_amdgcn_global_load_lds(                           \
      (__attribute__((address_space(1))) void*)(gp),          \
      (__attribute__((address_space(3))) void*)(lp), 16, 0, 0)

// ---------------------------------------------------------------- converts
__global__ void f32_to_bf16(const float* __restrict__ in, ushort_t* __restrict__ out,
                            size_t n4) {
  const size_t stride = (size_t)gridDim.x * blockDim.x;
  for (size_t i = (size_t)blockIdx.x * blockDim.x + threadIdx.x; i < n4; i += stride) {
    float4 f = ((const float4*)in)[i];
    uint_t lo = (uint_t)f2bf(f.x) | ((uint_t)f2bf(f.y) << 16);
    uint_t hi = (uint_t)f2bf(f.z) | ((uint_t)f2bf(f.w) << 16);
    ((uint2*)out)[i] = make_uint2(lo, hi);
  }
}

// ---------------------------------------------------------------- RoPE (in place, bf16 [M][E])
__global__ void rope_k(ushort_t* __restrict__ T) {
  const size_t total = (size_t)M_ * (E_ / 8);
  const size_t stride = (size_t)gridDim.x * blockDim.x;
  for (size_t c = (size_t)blockIdx.x * blockDim.x + threadIdx.x; c < total; c += stride) {
    const int row = (int)(c >> 8);
    const int ch = (int)(c & 255);
    const int s = row & (S_ - 1);
    const int p0 = ((ch * 8) & (D_ - 1)) >> 1;
    ushort_t* p = T + ((size_t)row << 11) + ch * 8;
    bf16x8 v = *(bf16x8*)p;
#pragma unroll
    for (int j = 0; j < 4; j++) {
      const int ip = p0 + j;
      const float inv = __expf(-0.14391156963595867f * (float)ip);  // 10000^(-2ip/128)
      const float ang = (float)s * inv;
      float sn, cs;
      sincosf(ang, &sn, &cs);
      const float xe = bf2f((ushort_t)v[2 * j]);
      const float xo = bf2f((ushort_t)v[2 * j + 1]);
      v[2 * j] = (short)f2bf(xe * cs - xo * sn);
      v[2 * j + 1] = (short)f2bf(xe * sn + xo * cs);
    }
    *(bf16x8*)p = v;
  }
}

// ---------------------------------------------------------------- V transpose: [M][E] -> [B][H][D][S]
__global__ __launch_bounds__(256) void transpose_v(const ushort_t* __restrict__ Vp,
                                                   ushort_t* __restrict__ Vt) {
  const int b = blockIdx.z, h = blockIdx.y;
  const int s0 = blockIdx.x * 64;
  const int tid = threadIdx.x;
  __shared__ ushort_t T[64][136];
#pragma unroll
  for (int i = 0; i < 4; i++) {
    const int c = i * 256 + tid;
    const int s = c >> 4, d8 = c & 15;
    *(bf16x8*)(&T[s][d8 * 8]) =
        *(const bf16x8*)(Vp + (size_t)(b * S_ + s0 + s) * E_ + h * D_ + d8 * 8);
  }
  __syncthreads();
#pragma unroll
  for (int i = 0; i < 4; i++) {
    const int c = i * 256 + tid;
    const int d = c >> 3, s8 = c & 7;
    bf16x8 v;
#pragma unroll
    for (int j = 0; j < 8; j++) v[j] = (short)T[s8 * 8 + j][d];
    *(bf16x8*)(Vt + ((size_t)(b * H_ + h) * D_ + d) * S_ + s0 + s8 * 8) = v;
  }
}

// ---------------------------------------------------------------- GEMM: C[M][N] = A[M][K]·Bw[N][K]^T + bias
template <int OUTF32>
__global__ __launch_bounds__(256, 2) void gemm_bt(const ushort_t* __restrict__ A,
                                                  const ushort_t* __restrict__ Bw,
                                                  const float* __restrict__ bias,
                                                  void* __restrict__ Cv) {
  __shared__ ushort_t As[128 * 64];
  __shared__ ushort_t Bs[128 * 64];
  const int tid = threadIdx.x;
  const int w = tid >> 6, l = tid & 63, g = l >> 4, ln = l & 15;
  const int wm = w >> 1, wn = w & 1;
  const int flat = blockIdx.y * 16 + blockIdx.x;
  const int swz = (flat & 7) * 128 + (flat >> 3);
  const int m0 = (swz >> 4) * 128, n0 = (swz & 15) * 128;

  f32x4 acc[4][4];
#pragma unroll
  for (int i = 0; i < 4; i++)
#pragma unroll
    for (int j = 0; j < 4; j++)
#pragma unroll
      for (int r = 0; r < 4; r++) acc[i][j][r] = 0.f;

  const ushort_t* Ab = A + (size_t)m0 * E_;
  const ushort_t* Bb = Bw + (size_t)n0 * E_;

  for (int k0 = 0; k0 < E_; k0 += 64) {
    __syncthreads();
#pragma unroll
    for (int i = 0; i < 4; i++) {
      const int c = i * 256 + tid;
      const int row = c >> 3;
      const int gs = (c & 7) ^ (row & 7);
      GLOAD_LDS16(Ab + (size_t)row * E_ + k0 + gs * 8, (char*)As + (i * 256 + w * 64) * 16);
      GLOAD_LDS16(Bb + (size_t)row * E_ + k0 + gs * 8, (char*)Bs + (i * 256 + w * 64) * 16);
    }
    __syncthreads();
#pragma unroll
    for (int kk = 0; kk < 2; kk++) {
      bf16x8 af[4], bfr[4];
#pragma unroll
      for (int mi = 0; mi < 4; mi++) {
        const int row = wm * 64 + mi * 16 + ln;
        const int sl = (kk * 4 + g) ^ (row & 7);
        af[mi] = *(const bf16x8*)(As + row * 64 + sl * 8);
      }
#pragma unroll
      for (int ni = 0; ni < 4; ni++) {
        const int row = wn * 64 + ni * 16 + ln;
        const int sl = (kk * 4 + g) ^ (row & 7);
        bfr[ni] = *(const bf16x8*)(Bs + row * 64 + sl * 8);
      }
#pragma unroll
      for (int mi = 0; mi < 4; mi++)
#pragma unroll
        for (int ni = 0; ni < 4; ni++)
          acc[mi][ni] =
              __builtin_amdgcn_mfma_f32_16x16x32_bf16(af[mi], bfr[ni], acc[mi][ni], 0, 0, 0);
    }
  }

  float bv[4];
#pragma unroll
  for (int ni = 0; ni < 4; ni++) bv[ni] = bias[n0 + wn * 64 + ni * 16 + ln];
#pragma unroll
  for (int mi = 0; mi < 4; mi++)
#pragma unroll
    for (int ni = 0; ni < 4; ni++)
#pragma unroll
      for (int r = 0; r < 4; r++) {
        const float v = acc[mi][ni][r] + bv[ni];
        const size_t row = m0 + wm * 64 + mi * 16 + g * 4 + r;
        const size_t col = n0 + wn * 64 + ni * 16 + ln;
        if (OUTF32)
          ((float*)Cv)[row * E_ + col] = v;
        else
          ((ushort_t*)Cv)[row * E_ + col] = f2bf(v);
      }
}

// ---------------------------------------------------------------- flash attention (causal), v3
// 256 thr / 4 waves, QBLK=128 (32 rows/wave), KVBLK=64. Balanced q-unit pairs
// (u, 15-u) -> constant 34 tiles/block; 512 blocks = 2/CU (LDS 80KB).
// Swapped QK^T (S^T fragments): 2-shfl softmax reduce, b64 P-writes into
// XOR-swizzled per-wave Ps, b128 P-reads as PV B-operand, b64 O stores.
// K/V double-buffered via global_load_lds with counted vmcnt(8) (T4), raw
// barriers, defer-max rescale (T13, THR=8).
__global__ __launch_bounds__(256, 2) void attn_fwd(const ushort_t* __restrict__ Q,
                                                   const ushort_t* __restrict__ K,
                                                   const ushort_t* __restrict__ Vt,
                                                   ushort_t* __restrict__ O) {
  const int b = blockIdx.z, h = blockIdx.y;
  const int pair = blockIdx.x;  // 0..7
  const int tid = threadIdx.x;
  const int w = tid >> 6, l = tid & 63, g = l >> 4, ln = l & 15;

  __shared__ ushort_t Ks[2][64 * 128];  // 32 KB
  __shared__ ushort_t Vs[2][128 * 64];  // 32 KB
  __shared__ ushort_t Ps[4][32 * 64];   // 16 KB, XOR-swizzled rows

  const ushort_t* Kb = K + (size_t)(b * S_) * E_ + h * D_;
  const ushort_t* Vb = Vt + (size_t)(b * H_ + h) * D_ * S_;
  const float scale = 0.08838834764831845f;  // D^-0.5

#define STAGE_KV(buf, kv0_)                                                      \
  do {                                                                           \
    _Pragma("unroll") for (int i = 0; i < 4; i++) {                              \
      const int c = i * 256 + tid;                                               \
      const int row = c >> 4, sl = c & 15;                                       \
      const int gs = sl ^ (row & 7);                                             \
      GLOAD_LDS16(Kb + (size_t)((kv0_) + row) * E_ + gs * 8,                     \
                  (char*)(&Ks[buf][0]) + (i * 256 + w * 64) * 16);               \
    }                                                                            \
    _Pragma("unroll") for (int i = 0; i < 4; i++) {                              \
      const int c = i * 256 + tid;                                               \
      const int row = c >> 3, sl = c & 7;                                        \
      const int gs = sl ^ (row & 7);                                             \
      GLOAD_LDS16(Vb + (size_t)row * S_ + (kv0_) + gs * 8,                       \
                  (char*)(&Vs[buf][0]) + (i * 256 + w * 64) * 16);               \
    }                                                                            \
  } while (0)

  for (int pass = 0; pass < 2; pass++) {
    const int u = (pass == 0) ? pair : (15 - pair);
    const int q0 = u * 128;
    const int wrow0 = q0 + w * 32;

    // Q fragments (B-operand layout: n=ln q-row, k=d), pre-scaled by 1/sqrt(D)
    bf16x8 qf[2][4];
    {
      const ushort_t* qb = Q + (size_t)(b * S_ + wrow0) * E_ + h * D_;
#pragma unroll
      for (int mi = 0; mi < 2; mi++)
#pragma unroll
        for (int kk = 0; kk < 4; kk++) {
          bf16x8 v = *(const bf16x8*)(qb + (size_t)(mi * 16 + ln) * E_ + kk * 32 + g * 8);
#pragma unroll
          for (int j = 0; j < 8; j++) v[j] = (short)f2bf(bf2f((ushort_t)v[j]) * scale);
          qf[mi][kk] = v;
        }
    }

    // oacc[mi][nd][r] = O[q = mi*16+ln][d = nd*16 + g*4 + r]  (O^T fragments)
    f32x4 oacc[2][8];
#pragma unroll
    for (int mi = 0; mi < 2; mi++)
#pragma unroll
      for (int nd = 0; nd < 8; nd++)
#pragma unroll
        for (int r = 0; r < 4; r++) oacc[mi][nd][r] = 0.f;
    float mrun[2], srun[2];
#pragma unroll
    for (int mi = 0; mi < 2; mi++) {
      mrun[mi] = -__builtin_inff();
      srun[mi] = 0.f;
    }

    const int ntu = 2 * u + 2;
    STAGE_KV(0, 0);

    for (int t = 0; t < ntu; t++) {
      const int kv0 = t * 64;
      const int cur = t & 1;
      if (t + 1 < ntu) {
        STAGE_KV(cur ^ 1, kv0 + 64);
        asm volatile("s_waitcnt vmcnt(8)" ::: "memory");  // tile t landed; t+1 in flight
      } else {
        asm volatile("s_waitcnt vmcnt(0)" ::: "memory");
      }
      __builtin_amdgcn_s_barrier();
      __builtin_amdgcn_sched_barrier(0);

      if (kv0 <= wrow0 + 31) {  // wave-level causal skip (kv0 <= wrow0 always when active)
        const ushort_t* Kst = &Ks[cur][0];
        const ushort_t* Vst = &Vs[cur][0];
        // ---- swapped QK^T: sa[mi][ni] = S^T frag [kv = ni*16+g*4+r][q = mi*16+ln]
        f32x4 sa[2][4];
#pragma unroll
        for (int mi = 0; mi < 2; mi++)
#pragma unroll
          for (int ni = 0; ni < 4; ni++)
#pragma unroll
            for (int r = 0; r < 4; r++) sa[mi][ni][r] = 0.f;
#pragma unroll
        for (int kk = 0; kk < 4; kk++) {
          bf16x8 kf[4];
#pragma unroll
          for (int ni = 0; ni < 4; ni++) {
            const int row = ni * 16 + ln;
            const int sl = (kk * 4 + g) ^ (row & 7);
            kf[ni] = *(const bf16x8*)(Kst + row * 128 + sl * 8);
          }
#pragma unroll
          for (int mi = 0; mi < 2; mi++)
#pragma unroll
            for (int ni = 0; ni < 4; ni++)
              sa[mi][ni] =
                  __builtin_amdgcn_mfma_f32_16x16x32_bf16(kf[ni], qf[mi][kk], sa[mi][ni], 0, 0, 0);
        }
        // ---- causal mask (diagonal tiles only): kv index > q-row index
        if (kv0 + 63 > wrow0) {
#pragma unroll
          for (int mi = 0; mi < 2; mi++) {
            const int lim = wrow0 + mi * 16 + ln - kv0;  // mask kvi > lim
#pragma unroll
            for (int ni = 0; ni < 4; ni++)
#pragma unroll
              for (int r = 0; r < 4; r++)
                if (ni * 16 + g * 4 + r > lim) sa[mi][ni][r] = -__builtin_inff();
          }
        }
        // ---- softmax per q-row (in-lane 16 + shfl_xor 16/32 across g-lanes)
#pragma unroll
        for (int mi = 0; mi < 2; mi++) {
          float vmax = -__builtin_inff();
#pragma unroll
          for (int ni = 0; ni < 4; ni++)
#pragma unroll
            for (int r = 0; r < 4; r++) vmax = fmaxf(vmax, sa[mi][ni][r]);
          vmax = fmaxf(vmax, __shfl_xor(vmax, 16));
          vmax = fmaxf(vmax, __shfl_xor(vmax, 32));
          if (!__all(vmax - mrun[mi] <= 8.0f)) {  // T13 defer-max, wave-uniform
            const float mnew = fmaxf(mrun[mi], vmax);
            const float fs = __expf(mrun[mi] - mnew);
            mrun[mi] = mnew;
            srun[mi] *= fs;
#pragma unroll
            for (int nd = 0; nd < 8; nd++)
#pragma unroll
              for (int r = 0; r < 4; r++) oacc[mi][nd][r] *= fs;
          }
          const float m = mrun[mi];
          float psum = 0.f;
#pragma unroll
          for (int ni = 0; ni < 4; ni++) {
            float p0 = __expf(sa[mi][ni][0] - m);
            float p1 = __expf(sa[mi][ni][1] - m);
            float p2 = __expf(sa[mi][ni][2] - m);
            float p3 = __expf(sa[mi][ni][3] - m);
            psum += (p0 + p1) + (p2 + p3);
            // b64 write: row q = mi*16+ln, cols kv = ni*16+g*4 .. +3, XOR swizzle
            const int byteW =
                (((mi * 16 + ln) * 64 + ni * 16 + g * 4) * 2) ^ ((ln & 7) << 4);
            *(uint2*)((char*)(&Ps[w][0]) + byteW) =
                make_uint2(cvt_pk_bf16(p0, p1), cvt_pk_bf16(p2, p3));
          }
          psum += __shfl_xor(psum, 16);
          psum += __shfl_xor(psum, 32);
          srun[mi] += psum;
        }
        asm volatile("s_waitcnt lgkmcnt(0)" ::: "memory");  // per-wave P write->read
        __builtin_amdgcn_sched_barrier(0);
        // ---- PV: oacc[mi][nd] += V^T-frag · P^T-frag
#pragma unroll
        for (int ks = 0; ks < 2; ks++) {
          bf16x8 pf[2];
#pragma unroll
          for (int mi = 0; mi < 2; mi++) {
            const int byteR =
                (((mi * 16 + ln) * 64 + ks * 32 + g * 8) * 2) ^ ((ln & 7) << 4);
            pf[mi] = *(const bf16x8*)((const char*)(&Ps[w][0]) + byteR);
          }
#pragma unroll
          for (int nd = 0; nd < 8; nd++) {
            const int row = nd * 16 + ln;
            const int sl = (ks * 4 + g) ^ (row & 7);
            const bf16x8 vf = *(const bf16x8*)(Vst + row * 64 + sl * 8);
#pragma unroll
            for (int mi = 0; mi < 2; mi++)
              oacc[mi][nd] =
                  __builtin_amdgcn_mfma_f32_16x16x32_bf16(vf, pf[mi], oacc[mi][nd], 0, 0, 0);
          }
        }
      }
      __builtin_amdgcn_s_barrier();  // all reads of buf[cur] done -> next STAGE may overwrite
    }

    // ---- epilogue: b64 stores, 4 consecutive d per lane
    {
      ushort_t* Ob = O + (size_t)(b * S_ + wrow0) * E_ + h * D_;
#pragma unroll
      for (int mi = 0; mi < 2; mi++) {
        const float inv = 1.0f / srun[mi];
#pragma unroll
        for (int nd = 0; nd < 8; nd++) {
          const uint_t lo = cvt_pk_bf16(oacc[mi][nd][0] * inv, oacc[mi][nd][1] * inv);
          const uint_t hi = cvt_pk_bf16(oacc[mi][nd][2] * inv, oacc[mi][nd][3] * inv);
          *(uint2*)(Ob + (size_t)(mi * 16 + ln) * E_ + nd * 16 + g * 4) = make_uint2(lo, hi);
        }
      }
    }
  }
#undef STAGE_KV
}

// ---------------------------------------------------------------- launch
extern "C" void kernel_launch(void* const* d_in, const int* in_sizes, int n_in,
                              void* d_out, int out_size, void* d_ws, size_t ws_size,
                              hipStream_t stream) {
  const float* x = (const float*)d_in[0];
  const float* Wq = (const float*)d_in[1];
  const float* bq = (const float*)d_in[2];
  const float* Wk = (const float*)d_in[3];
  const float* bk = (const float*)d_in[4];
  const float* Wv = (const float*)d_in[5];
  const float* bv = (const float*)d_in[6];
  const float* Wo = (const float*)d_in[7];
  const float* bo = (const float*)d_in[8];
  float* out = (float*)d_out;

  ushort_t* ws = (ushort_t*)d_ws;
  const size_t SZ = (size_t)M_ * E_;   // 16,777,216
  const size_t WSZ = (size_t)E_ * E_;  // 4,194,304
  ushort_t* xb = ws;            // x bf16; reused as attention output after projections
  ushort_t* Qb = ws + SZ;
  ushort_t* Kb = ws + 2 * SZ;
  ushort_t* Vb = ws + 3 * SZ;
  ushort_t* Vtb = ws + 4 * SZ;
  ushort_t* Wqb = ws + 5 * SZ;
  ushort_t* Wkb = Wqb + WSZ;
  ushort_t* Wvb = Wkb + WSZ;
  ushort_t* Wob = Wvb + WSZ;
  ushort_t* Ob = xb;

  f32_to_bf16<<<2048, 256, 0, stream>>>(x, xb, SZ / 4);
  f32_to_bf16<<<1024, 256, 0, stream>>>(Wq, Wqb, WSZ / 4);
  f32_to_bf16<<<1024, 256, 0, stream>>>(Wk, Wkb, WSZ / 4);
  f32_to_bf16<<<1024, 256, 0, stream>>>(Wv, Wvb, WSZ / 4);
  f32_to_bf16<<<1024, 256, 0, stream>>>(Wo, Wob, WSZ / 4);

  dim3 gg(16, 64);
  gemm_bt<0><<<gg, 256, 0, stream>>>(xb, Wqb, bq, Qb);
  gemm_bt<0><<<gg, 256, 0, stream>>>(xb, Wkb, bk, Kb);
  gemm_bt<0><<<gg, 256, 0, stream>>>(xb, Wvb, bv, Vb);

  rope_k<<<2048, 256, 0, stream>>>(Qb);
  rope_k<<<2048, 256, 0, stream>>>(Kb);
  transpose_v<<<dim3(32, H_, B_), 256, 0, stream>>>(Vb, Vtb);

  attn_fwd<<<dim3(8, H_, B_), 256, 0, stream>>>(Qb, Kb, Vtb, Ob);

  gemm_bt<1><<<gg, 256, 0, stream>>>(Ob, Wob, bo, (void*)out);
}